// Round 4
// baseline (615.438 us; speedup 1.0000x reference)
//
#include <hip/hip_runtime.h>
#include <hip/hip_bf16.h>
#include <cstdint>

#define B_  2
#define C_  128
#define HH  128
#define WW  128
#define L_  4096
#define K1  1152
#define M2  2048
#define NCAND 16
#define MARGIN 0.15f
#define PCUT 1e-5f
#define MAXC 512

typedef __attribute__((ext_vector_type(8))) short bf16x8s;
typedef __attribute__((ext_vector_type(4))) float f32x4;
using bf16 = __hip_bfloat16;

__device__ inline float bf16bits2f(short s) {
  uint32_t u = ((uint32_t)(uint16_t)s) << 16;
  return __builtin_bit_cast(float, u);
}

__device__ inline void gload_lds16(const void* g, void* l) {
  auto gp = reinterpret_cast<const __attribute__((address_space(1))) uint32_t*>(
      reinterpret_cast<uintptr_t>(g));
  auto lp = reinterpret_cast<__attribute__((address_space(3))) uint32_t*>(
      reinterpret_cast<uintptr_t>(l));
  __builtin_amdgcn_global_load_lds(gp, lp, 16, 0, 0);
}

// ---------------- mask validity: mm[l] = 1 if 3x3 patch of ms (batch 0) sums to 0
__global__ void compute_mm_k(const float* __restrict__ mask, float* __restrict__ mm) {
  int l = blockIdx.x * 256 + threadIdx.x;
  if (l >= L_) return;
  int i = l >> 6, j = l & 63;
  float s = 0.f;
  for (int p = -1; p <= 1; ++p)
    for (int q = -1; q <= 1; ++q) {
      int y = i + p, x = j + q;
      if ((unsigned)y < 64u && (unsigned)x < 64u)
        s += mask[(size_t)(8 * y) * 512 + 8 * x];
    }
  mm[l] = (s == 0.f) ? 1.f : 0.f;
}

// ---------------- U[l][k] : normalized bs-patches (bf16) + fp32 denominators
__global__ __launch_bounds__(256) void prep_u_k(const float* __restrict__ bsrc,
                                                bf16* __restrict__ U,
                                                float* __restrict__ normden, int bi) {
  __shared__ float red[4];
  int l = blockIdx.x;
  int i = l >> 6, j = l & 63;
  int t = threadIdx.x;
  float vals[5];
  float ss = 0.f;
#pragma unroll
  for (int s = 0; s < 5; ++s) {
    int k = t + s * 256;
    float v = 0.f;
    if (k < K1) {
      int c = k / 9, r = k - c * 9;
      int p = r / 3, q = r - p * 3;
      int y = i + p - 1, x = j + q - 1;
      if ((unsigned)y < 64u && (unsigned)x < 64u)
        v = bsrc[(((size_t)bi * C_ + c) * HH + 2 * y) * WW + 2 * x];
    }
    vals[s] = v;
    ss += v * v;
  }
#pragma unroll
  for (int o = 32; o; o >>= 1) ss += __shfl_xor(ss, o);
  if ((t & 63) == 0) red[t >> 6] = ss;
  __syncthreads();
  float tot = red[0] + red[1] + red[2] + red[3];
  float den = fmaxf(sqrtf(tot), 1e-4f);
  float inv = 1.f / den;
  if (t == 0) normden[l] = den;
  size_t base = (size_t)l * K1;
#pragma unroll
  for (int s = 0; s < 5; ++s) {
    int k = t + s * 256;
    if (k < K1) U[base + k] = __float2bfloat16(vals[s] * inv);
  }
}

// ---------------- FP[hw][k] : fs-patches (bf16)
__global__ __launch_bounds__(256) void prep_fp_k(const float* __restrict__ f,
                                                 bf16* __restrict__ FP, int bi) {
  int idx = blockIdx.x * 256 + threadIdx.x;
  if (idx >= L_ * K1) return;
  int hw = idx / K1, k = idx - hw * K1;
  int h = hw >> 6, w = hw & 63;
  int c = k / 9, r = k - c * 9;
  int p = r / 3, q = r - p * 3;
  int y = h + p - 1, x = w + q - 1;
  float v = 0.f;
  if ((unsigned)y < 64u && (unsigned)x < 64u)
    v = f[(((size_t)bi * C_ + c) * HH + 2 * y) * WW + 2 * x];
  FP[(size_t)hw * K1 + k] = __float2bfloat16(v);
}

// ---------------- BmT[l][m] = b[c, 2i+p-1, 2j+q-1], m=(c,p,q), coalesced writes
__global__ void prep_bmatT_k(const float* __restrict__ bsrc, bf16* __restrict__ BmT, int bi) {
  int idx = blockIdx.x * 256 + threadIdx.x;
  if (idx >= M2 * L_) return;
  int l = idx >> 11, m = idx & 2047;
  int c = m >> 4, p = (m >> 2) & 3, q = m & 3;
  int i = l >> 6, j = l & 63;
  int y = 2 * i + p - 1, x = 2 * j + q - 1;
  float v = 0.f;
  if ((unsigned)y < 128u && (unsigned)x < 128u)
    v = bsrc[(((size_t)bi * C_ + c) * HH + y) * WW + x];
  BmT[idx] = __float2bfloat16(v);
}

// ---------------- GEMM: C[m][n] = sum_k A[m*K+k]*B[n*K+k], bf16 in, f32 out
__global__ __launch_bounds__(256) void gemm_bt(const bf16* __restrict__ A,
                                               const bf16* __restrict__ B,
                                               float* __restrict__ C,
                                               int M, int N, int K) {
  __shared__ __align__(16) bf16 sA[2][128][32];
  __shared__ __align__(16) bf16 sB[2][128][32];
  const int tid = threadIdx.x;
  const int lane = tid & 63;
  const int wid = tid >> 6;
  const int bm = blockIdx.x * 128;
  const int bn = blockIdx.y * 128;
  const int wm = (wid >> 1) * 64;
  const int wn = (wid & 1) * 64;
  const int lrow = lane & 15;
  const int lko = (lane >> 4) * 8;

  f32x4 acc[4][4];
#pragma unroll
  for (int i = 0; i < 4; ++i)
#pragma unroll
    for (int j = 0; j < 4; ++j) acc[i][j] = (f32x4){0.f, 0.f, 0.f, 0.f};

  const int nt = K >> 5;
  const int s0 = tid, s1 = tid + 256;
  const int ar0 = s0 >> 2, ac0 = (s0 & 3) * 8;
  const int ar1 = s1 >> 2, ac1 = (s1 & 3) * 8;

  auto STAGE = [&](int bufi, int t) {
    const int k0 = t * 32;
    gload_lds16(A + (size_t)(bm + ar0) * K + k0 + ac0, &sA[bufi][ar0][ac0]);
    gload_lds16(A + (size_t)(bm + ar1) * K + k0 + ac1, &sA[bufi][ar1][ac1]);
    gload_lds16(B + (size_t)(bn + ar0) * K + k0 + ac0, &sB[bufi][ar0][ac0]);
    gload_lds16(B + (size_t)(bn + ar1) * K + k0 + ac1, &sB[bufi][ar1][ac1]);
  };

  STAGE(0, 0);
  __syncthreads();
  int buf = 0;
  for (int t = 0; t < nt; ++t) {
    if (t + 1 < nt) STAGE(buf ^ 1, t + 1);
    bf16x8s af[4], bfr[4];
#pragma unroll
    for (int fm = 0; fm < 4; ++fm)
      af[fm] = *(const bf16x8s*)&sA[buf][wm + fm * 16 + lrow][lko];
#pragma unroll
    for (int fn = 0; fn < 4; ++fn)
      bfr[fn] = *(const bf16x8s*)&sB[buf][wn + fn * 16 + lrow][lko];
#pragma unroll
    for (int fm = 0; fm < 4; ++fm)
#pragma unroll
      for (int fn = 0; fn < 4; ++fn)
        acc[fm][fn] = __builtin_amdgcn_mfma_f32_16x16x32_bf16(af[fm], bfr[fn], acc[fm][fn], 0, 0, 0);
    __syncthreads();
    buf ^= 1;
  }

  const int crow = (lane >> 4) * 4;
  const int ccol = lane & 15;
#pragma unroll
  for (int fm = 0; fm < 4; ++fm)
#pragma unroll
    for (int fn = 0; fn < 4; ++fn) {
      int r0 = bm + wm + fm * 16 + crow;
      int c0 = bn + wn + fn * 16 + ccol;
#pragma unroll
      for (int r = 0; r < 4; ++r)
        C[(size_t)(r0 + r) * N + c0] = acc[fm][fn][r];
    }
}

// ---------------- fused per-row softmax + sparse PV + candidate collection
// Zt[hw][m] = sum_l p[l] * BmT[l][m], only over p >= PCUT (tail mass ~<3e-2)
__global__ __launch_bounds__(256) void softmax_spmv_k(const float* __restrict__ S,
                                                      const float* __restrict__ mm,
                                                      const bf16* __restrict__ BmT,
                                                      float* __restrict__ Zt,
                                                      int* __restrict__ cand,
                                                      int* __restrict__ candcnt) {
  __shared__ float rmax[4];
  __shared__ float rbv[4];
  __shared__ float rsum[4];
  __shared__ int scnt, mcnt;
  __shared__ int slist[MAXC];
  __shared__ float splist[MAXC];
  __shared__ int mlist[NCAND];
  const int row = blockIdx.x;
  const int t = threadIdx.x;
  if (t == 0) { scnt = 0; mcnt = 0; }
  const float* srow = S + (size_t)row * L_;
  float xs[16];
  float msk[16];
  float gmax = -1e30f, bv = -1e30f;
#pragma unroll
  for (int s = 0; s < 16; ++s) {
    int l = t + s * 256;
    float x = srow[l];
    float m = mm[l];
    xs[s] = x;
    msk[s] = m;
    gmax = fmaxf(gmax, x * m);
    if (m != 0.f) bv = fmaxf(bv, x);
  }
#pragma unroll
  for (int o = 32; o; o >>= 1) {
    gmax = fmaxf(gmax, __shfl_xor(gmax, o));
    bv = fmaxf(bv, __shfl_xor(bv, o));
  }
  if ((t & 63) == 0) { rmax[t >> 6] = gmax; rbv[t >> 6] = bv; }
  __syncthreads();
  gmax = fmaxf(fmaxf(rmax[0], rmax[1]), fmaxf(rmax[2], rmax[3]));
  bv = fmaxf(fmaxf(rbv[0], rbv[1]), fmaxf(rbv[2], rbv[3]));
  // denominator (identical semantics to ref: all 4096 entries incl. masked-at-0)
  float zs = 0.f;
#pragma unroll
  for (int s = 0; s < 16; ++s) zs += __expf(10.f * (xs[s] * msk[s] - gmax));
#pragma unroll
  for (int o = 32; o; o >>= 1) zs += __shfl_xor(zs, o);
  if ((t & 63) == 0) rsum[t >> 6] = zs;
  __syncthreads();
  zs = rsum[0] + rsum[1] + rsum[2] + rsum[3];
  float invZ = 1.f / zs;
  // p >= PCUT  <=>  x >= gmax + ln(PCUT*Z)/10
  float cutx = gmax + __logf(PCUT * zs) * 0.1f;
#pragma unroll
  for (int s = 0; s < 16; ++s) {
    int l = t + s * 256;
    if (msk[s] != 0.f) {
      if (xs[s] >= cutx) {
        int pos = atomicAdd(&scnt, 1);
        if (pos < MAXC) {
          slist[pos] = l;
          splist[pos] = __expf(10.f * (xs[s] - gmax)) * invZ;
        }
      }
      if (xs[s] >= bv - MARGIN) {
        int pos = atomicAdd(&mcnt, 1);
        if (pos < NCAND) mlist[pos] = l;
      }
    }
  }
  __syncthreads();
  int nc = min(scnt, MAXC);
  float acc[8] = {0.f, 0.f, 0.f, 0.f, 0.f, 0.f, 0.f, 0.f};
  for (int ci = 0; ci < nc; ++ci) {
    int l = slist[ci];
    float p = splist[ci];
    bf16x8s bv8 = *(const bf16x8s*)&BmT[(size_t)l * M2 + t * 8];
#pragma unroll
    for (int j = 0; j < 8; ++j) {
      short e = bv8[j];
      acc[j] += p * bf16bits2f(e);
    }
  }
  float* zrow = Zt + (size_t)row * M2 + t * 8;
#pragma unroll
  for (int j = 0; j < 8; ++j) zrow[j] = acc[j];
  if (t == 0) candcnt[row] = min(mcnt, NCAND);
  if (t < NCAND && t < mcnt) cand[row * NCAND + t] = mlist[t];
}

// ---------------- exact fp32 rescore of candidates -> argmax offsets
__global__ __launch_bounds__(64) void rescore_k(const float* __restrict__ f,
                                                const float* __restrict__ bsrc,
                                                const float* __restrict__ normden,
                                                const int* __restrict__ cand,
                                                const int* __restrict__ candcnt,
                                                float* __restrict__ offout, int bi) {
  const int row = blockIdx.x;
  const int lane = threadIdx.x;
  const int h = row >> 6, w = row & 63;
  int cnt = candcnt[row];
  int bestl = 0;
  if (cnt <= 1) {
    bestl = cand[row * NCAND];
  } else {
    float bestv = -1e30f;
    bestl = 0x7fffffff;
    for (int ci = 0; ci < cnt; ++ci) {
      int l = cand[row * NCAND + ci];
      int i = l >> 6, j = l & 63;
      float dot = 0.f;
#pragma unroll
      for (int cc = 0; cc < 2; ++cc) {
        int ch = lane + 64 * cc;
        const float* fb = f + (((size_t)bi * C_ + ch) * HH) * WW;
        const float* bb = bsrc + (((size_t)bi * C_ + ch) * HH) * WW;
#pragma unroll
        for (int p = 0; p < 3; ++p)
#pragma unroll
          for (int q = 0; q < 3; ++q) {
            int y1 = h + p - 1, x1 = w + q - 1;
            int y2 = i + p - 1, x2 = j + q - 1;
            if ((unsigned)y1 < 64u && (unsigned)x1 < 64u &&
                (unsigned)y2 < 64u && (unsigned)x2 < 64u)
              dot += fb[(size_t)(2 * y1) * WW + 2 * x1] * bb[(size_t)(2 * y2) * WW + 2 * x2];
          }
      }
#pragma unroll
      for (int o = 32; o; o >>= 1) dot += __shfl_xor(dot, o);
      float s = dot / normden[l];
      if (s > bestv || (s == bestv && l < bestl)) { bestv = s; bestl = l; }
    }
  }
  if (lane == 0) {
    int istar = bestl >> 6, jstar = bestl & 63;
    offout[(size_t)bi * 8192 + row] = (float)(istar - h);
    offout[(size_t)bi * 8192 + L_ + row] = (float)(jstar - w);
  }
}

// ---------------- final transposed-conv gather from Zt[hw][m]
__global__ void gather_k(const float* __restrict__ Zt, float* __restrict__ yout, int bi) {
  int u = blockIdx.x, c = blockIdx.y;
  int t = threadIdx.x;  // 64 threads, each handles v=2t and v=2t+1
  int h0 = (u + 1) >> 1, p0 = (u + 1) & 1;
  int h1 = h0 - 1, p1 = p0 + 2;
  float a0 = 0.f, a1 = 0.f;
#pragma unroll
  for (int e = 0; e < 2; ++e) {
    int h = e ? h1 : h0;
    int p = e ? p1 : p0;
    if ((unsigned)h < 64u) {
      const float* zb = Zt + (size_t)(h * 64) * M2 + c * 16 + p * 4;
      a0 += zb[(size_t)t * M2 + 1];                       // v=2t:   q=1, w=t
      if (t >= 1) a0 += zb[(size_t)(t - 1) * M2 + 3];     // v=2t:   q=3, w=t-1
      if (t < 63) a1 += zb[(size_t)(t + 1) * M2 + 0];     // v=2t+1: q=0, w=t+1
      a1 += zb[(size_t)t * M2 + 2];                       // v=2t+1: q=2, w=t
    }
  }
  size_t ybase = (((size_t)bi * C_ + c) * HH + u) * WW;
  yout[ybase + 2 * t] = a0 * 0.25f;
  yout[ybase + 2 * t + 1] = a1 * 0.25f;
}

extern "C" void kernel_launch(void* const* d_in, const int* in_sizes, int n_in,
                              void* d_out, int out_size, void* d_ws, size_t ws_size,
                              hipStream_t stream) {
  const float* f = (const float*)d_in[0];
  const float* b = (const float*)d_in[1];
  const float* mask = (const float*)d_in[2];
  float* out = (float*)d_out;
  char* ws = (char*)d_ws;

  size_t off = 0;
  float* mm = (float*)(ws + off);       off += 16384;
  float* normden = (float*)(ws + off);  off += 16384;
  int* cand = (int*)(ws + off);         off += (size_t)L_ * NCAND * 4;  // 256KB
  int* candcnt = (int*)(ws + off);      off += 16384;
  bf16* U = (bf16*)(ws + off);          off += (size_t)L_ * K1 * 2;     // 9.4MB
  bf16* FP = (bf16*)(ws + off);         off += (size_t)L_ * K1 * 2;     // 9.4MB
  bf16* BmT = (bf16*)(ws + off);        off += (size_t)M2 * L_ * 2;     // 16.8MB
  float* S = (float*)(ws + off);        off += (size_t)L_ * L_ * 4;     // 67.1MB
  float* Zt = (float*)(ws + off);       off += (size_t)M2 * L_ * 4;     // 33.5MB
  float* yout = out;
  float* offout = out + (size_t)B_ * C_ * HH * WW;

  compute_mm_k<<<16, 256, 0, stream>>>(mask, mm);
  for (int bi = 0; bi < B_; ++bi) {
    prep_u_k<<<L_, 256, 0, stream>>>(b, U, normden, bi);
    prep_fp_k<<<(L_ * K1 + 255) / 256, 256, 0, stream>>>(f, FP, bi);
    prep_bmatT_k<<<(M2 * L_ + 255) / 256, 256, 0, stream>>>(b, BmT, bi);
    gemm_bt<<<dim3(32, 32), 256, 0, stream>>>(FP, U, S, L_, L_, K1);
    softmax_spmv_k<<<L_, 256, 0, stream>>>(S, mm, BmT, Zt, cand, candcnt);
    rescore_k<<<L_, 64, 0, stream>>>(f, b, normden, cand, candcnt, offout, bi);
    gather_k<<<dim3(128, 128), 64, 0, stream>>>(Zt, yout, bi);
  }
}

// Round 5
// 520.734 us; speedup vs baseline: 1.1819x; 1.1819x over previous
//
#include <hip/hip_runtime.h>
#include <hip/hip_bf16.h>
#include <cstdint>

#define B_  2
#define C_  128
#define HH  128
#define WW  128
#define L_  4096
#define K1  1152
#define M2  2048
#define NCAND 16
#define MARGIN 0.15f
#define PCUT 1e-5f
#define MAXC 512

typedef __attribute__((ext_vector_type(8))) short bf16x8s;
typedef __attribute__((ext_vector_type(4))) float f32x4;
using bf16 = __hip_bfloat16;

__device__ inline float bf16bits2f(short s) {
  uint32_t u = ((uint32_t)(uint16_t)s) << 16;
  return __builtin_bit_cast(float, u);
}

__device__ inline void gload_lds16(const void* g, void* l) {
  auto gp = reinterpret_cast<const __attribute__((address_space(1))) uint32_t*>(
      reinterpret_cast<uintptr_t>(g));
  auto lp = reinterpret_cast<__attribute__((address_space(3))) uint32_t*>(
      reinterpret_cast<uintptr_t>(l));
  __builtin_amdgcn_global_load_lds(gp, lp, 16, 0, 0);
}

// ---------------- mask validity: mm[l] = 1 if 3x3 patch of ms (batch 0) sums to 0
__global__ void compute_mm_k(const float* __restrict__ mask, float* __restrict__ mm) {
  int l = blockIdx.x * 256 + threadIdx.x;
  if (l >= L_) return;
  int i = l >> 6, j = l & 63;
  float s = 0.f;
  for (int p = -1; p <= 1; ++p)
    for (int q = -1; q <= 1; ++q) {
      int y = i + p, x = j + q;
      if ((unsigned)y < 64u && (unsigned)x < 64u)
        s += mask[(size_t)(8 * y) * 512 + 8 * x];
    }
  mm[l] = (s == 0.f) ? 1.f : 0.f;
}

// ---------------- U[l][k] : normalized bs-patches (bf16) + fp32 denominators
__global__ __launch_bounds__(256) void prep_u_k(const float* __restrict__ bsrc,
                                                bf16* __restrict__ U,
                                                float* __restrict__ normden, int bi) {
  __shared__ float red[4];
  int l = blockIdx.x;
  int i = l >> 6, j = l & 63;
  int t = threadIdx.x;
  float vals[5];
  float ss = 0.f;
#pragma unroll
  for (int s = 0; s < 5; ++s) {
    int k = t + s * 256;
    float v = 0.f;
    if (k < K1) {
      int c = k / 9, r = k - c * 9;
      int p = r / 3, q = r - p * 3;
      int y = i + p - 1, x = j + q - 1;
      if ((unsigned)y < 64u && (unsigned)x < 64u)
        v = bsrc[(((size_t)bi * C_ + c) * HH + 2 * y) * WW + 2 * x];
    }
    vals[s] = v;
    ss += v * v;
  }
#pragma unroll
  for (int o = 32; o; o >>= 1) ss += __shfl_xor(ss, o);
  if ((t & 63) == 0) red[t >> 6] = ss;
  __syncthreads();
  float tot = red[0] + red[1] + red[2] + red[3];
  float den = fmaxf(sqrtf(tot), 1e-4f);
  float inv = 1.f / den;
  if (t == 0) normden[l] = den;
  size_t base = (size_t)l * K1;
#pragma unroll
  for (int s = 0; s < 5; ++s) {
    int k = t + s * 256;
    if (k < K1) U[base + k] = __float2bfloat16(vals[s] * inv);
  }
}

// ---------------- FP[hw][k] : fs-patches (bf16)
__global__ __launch_bounds__(256) void prep_fp_k(const float* __restrict__ f,
                                                 bf16* __restrict__ FP, int bi) {
  int idx = blockIdx.x * 256 + threadIdx.x;
  if (idx >= L_ * K1) return;
  int hw = idx / K1, k = idx - hw * K1;
  int h = hw >> 6, w = hw & 63;
  int c = k / 9, r = k - c * 9;
  int p = r / 3, q = r - p * 3;
  int y = h + p - 1, x = w + q - 1;
  float v = 0.f;
  if ((unsigned)y < 64u && (unsigned)x < 64u)
    v = f[(((size_t)bi * C_ + c) * HH + 2 * y) * WW + 2 * x];
  FP[(size_t)hw * K1 + k] = __float2bfloat16(v);
}

// ---------------- BmT[l][m] = b[c, 2i+p-1, 2j+q-1], m=(c,p,q), coalesced writes
__global__ void prep_bmatT_k(const float* __restrict__ bsrc, bf16* __restrict__ BmT, int bi) {
  int idx = blockIdx.x * 256 + threadIdx.x;
  if (idx >= M2 * L_) return;
  int l = idx >> 11, m = idx & 2047;
  int c = m >> 4, p = (m >> 2) & 3, q = m & 3;
  int i = l >> 6, j = l & 63;
  int y = 2 * i + p - 1, x = 2 * j + q - 1;
  float v = 0.f;
  if ((unsigned)y < 128u && (unsigned)x < 128u)
    v = bsrc[(((size_t)bi * C_ + c) * HH + y) * WW + x];
  BmT[idx] = __float2bfloat16(v);
}

// ---------------- GEMM: C[m][n] = sum_k A[m*K+k]*B[n*K+k], bf16 in, f32 out
__global__ __launch_bounds__(256) void gemm_bt(const bf16* __restrict__ A,
                                               const bf16* __restrict__ B,
                                               float* __restrict__ C,
                                               int M, int N, int K) {
  __shared__ __align__(16) bf16 sA[2][128][32];
  __shared__ __align__(16) bf16 sB[2][128][32];
  const int tid = threadIdx.x;
  const int lane = tid & 63;
  const int wid = tid >> 6;
  const int bm = blockIdx.x * 128;
  const int bn = blockIdx.y * 128;
  const int wm = (wid >> 1) * 64;
  const int wn = (wid & 1) * 64;
  const int lrow = lane & 15;
  const int lko = (lane >> 4) * 8;

  f32x4 acc[4][4];
#pragma unroll
  for (int i = 0; i < 4; ++i)
#pragma unroll
    for (int j = 0; j < 4; ++j) acc[i][j] = (f32x4){0.f, 0.f, 0.f, 0.f};

  const int nt = K >> 5;
  const int s0 = tid, s1 = tid + 256;
  const int ar0 = s0 >> 2, ac0 = (s0 & 3) * 8;
  const int ar1 = s1 >> 2, ac1 = (s1 & 3) * 8;

  auto STAGE = [&](int bufi, int t) {
    const int k0 = t * 32;
    gload_lds16(A + (size_t)(bm + ar0) * K + k0 + ac0, &sA[bufi][ar0][ac0]);
    gload_lds16(A + (size_t)(bm + ar1) * K + k0 + ac1, &sA[bufi][ar1][ac1]);
    gload_lds16(B + (size_t)(bn + ar0) * K + k0 + ac0, &sB[bufi][ar0][ac0]);
    gload_lds16(B + (size_t)(bn + ar1) * K + k0 + ac1, &sB[bufi][ar1][ac1]);
  };

  STAGE(0, 0);
  __syncthreads();
  int buf = 0;
  for (int t = 0; t < nt; ++t) {
    if (t + 1 < nt) STAGE(buf ^ 1, t + 1);
    bf16x8s af[4], bfr[4];
#pragma unroll
    for (int fm = 0; fm < 4; ++fm)
      af[fm] = *(const bf16x8s*)&sA[buf][wm + fm * 16 + lrow][lko];
#pragma unroll
    for (int fn = 0; fn < 4; ++fn)
      bfr[fn] = *(const bf16x8s*)&sB[buf][wn + fn * 16 + lrow][lko];
#pragma unroll
    for (int fm = 0; fm < 4; ++fm)
#pragma unroll
      for (int fn = 0; fn < 4; ++fn)
        acc[fm][fn] = __builtin_amdgcn_mfma_f32_16x16x32_bf16(af[fm], bfr[fn], acc[fm][fn], 0, 0, 0);
    __syncthreads();
    buf ^= 1;
  }

  const int crow = (lane >> 4) * 4;
  const int ccol = lane & 15;
#pragma unroll
  for (int fm = 0; fm < 4; ++fm)
#pragma unroll
    for (int fn = 0; fn < 4; ++fn) {
      int r0 = bm + wm + fm * 16 + crow;
      int c0 = bn + wn + fn * 16 + ccol;
#pragma unroll
      for (int r = 0; r < 4; ++r)
        C[(size_t)(r0 + r) * N + c0] = acc[fm][fn][r];
    }
}

// ---------------- fused per-row softmax + sparse PV + candidate collection
// Zt[hw][m] = sum_l p[l] * BmT[l][m], only over p >= PCUT (tail mass ~<3e-2)
__global__ __launch_bounds__(256) void softmax_spmv_k(const float* __restrict__ S,
                                                      const float* __restrict__ mm,
                                                      const bf16* __restrict__ BmT,
                                                      float* __restrict__ Zt,
                                                      int* __restrict__ cand,
                                                      int* __restrict__ candcnt) {
  __shared__ float rmax[4];
  __shared__ float rbv[4];
  __shared__ float rsum[4];
  __shared__ int scnt, mcnt;
  __shared__ int slist[MAXC];
  __shared__ float splist[MAXC];
  __shared__ int mlist[NCAND];
  const int row = blockIdx.x;
  const int t = threadIdx.x;
  if (t == 0) { scnt = 0; mcnt = 0; }
  const float* srow = S + (size_t)row * L_;
  float xs[16];
  float msk[16];
  float gmax = -1e30f, bv = -1e30f;
#pragma unroll
  for (int s = 0; s < 16; ++s) {
    int l = t + s * 256;
    float x = srow[l];
    float m = mm[l];
    xs[s] = x;
    msk[s] = m;
    gmax = fmaxf(gmax, x * m);
    if (m != 0.f) bv = fmaxf(bv, x);
  }
#pragma unroll
  for (int o = 32; o; o >>= 1) {
    gmax = fmaxf(gmax, __shfl_xor(gmax, o));
    bv = fmaxf(bv, __shfl_xor(bv, o));
  }
  if ((t & 63) == 0) { rmax[t >> 6] = gmax; rbv[t >> 6] = bv; }
  __syncthreads();
  gmax = fmaxf(fmaxf(rmax[0], rmax[1]), fmaxf(rmax[2], rmax[3]));
  bv = fmaxf(fmaxf(rbv[0], rbv[1]), fmaxf(rbv[2], rbv[3]));
  // denominator (identical semantics to ref: all 4096 entries incl. masked-at-0)
  float zs = 0.f;
#pragma unroll
  for (int s = 0; s < 16; ++s) zs += __expf(10.f * (xs[s] * msk[s] - gmax));
#pragma unroll
  for (int o = 32; o; o >>= 1) zs += __shfl_xor(zs, o);
  if ((t & 63) == 0) rsum[t >> 6] = zs;
  __syncthreads();
  zs = rsum[0] + rsum[1] + rsum[2] + rsum[3];
  float invZ = 1.f / zs;
  // p >= PCUT  <=>  x >= gmax + ln(PCUT*Z)/10
  float cutx = gmax + __logf(PCUT * zs) * 0.1f;
#pragma unroll
  for (int s = 0; s < 16; ++s) {
    int l = t + s * 256;
    if (msk[s] != 0.f) {
      if (xs[s] >= cutx) {
        int pos = atomicAdd(&scnt, 1);
        if (pos < MAXC) {
          slist[pos] = l;
          splist[pos] = __expf(10.f * (xs[s] - gmax)) * invZ;
        }
      }
      if (xs[s] >= bv - MARGIN) {
        int pos = atomicAdd(&mcnt, 1);
        if (pos < NCAND) mlist[pos] = l;
      }
    }
  }
  __syncthreads();
  int nc = min(scnt, MAXC);
  float acc[8] = {0.f, 0.f, 0.f, 0.f, 0.f, 0.f, 0.f, 0.f};
  for (int ci = 0; ci < nc; ++ci) {
    int l = slist[ci];
    float p = splist[ci];
    bf16x8s bv8 = *(const bf16x8s*)&BmT[(size_t)l * M2 + t * 8];
#pragma unroll
    for (int j = 0; j < 8; ++j) {
      short e = bv8[j];
      acc[j] += p * bf16bits2f(e);
    }
  }
  float* zrow = Zt + (size_t)row * M2 + t * 8;
#pragma unroll
  for (int j = 0; j < 8; ++j) zrow[j] = acc[j];
  if (t == 0) candcnt[row] = min(mcnt, NCAND);
  if (t < NCAND && t < mcnt) cand[row * NCAND + t] = mlist[t];
}

// ---------------- LDS-tiled transpose: Zt[hw][m] -> Z2[m][hw]
__global__ __launch_bounds__(256) void transpose_k(const float* __restrict__ in,
                                                   float* __restrict__ out) {
  __shared__ float tile[32][33];
  int bm = blockIdx.x * 32;   // m tile
  int bh = blockIdx.y * 32;   // hw tile
  int tx = threadIdx.x & 31;
  int ty = threadIdx.x >> 5;  // 0..7
#pragma unroll
  for (int r = 0; r < 32; r += 8)
    tile[ty + r][tx] = in[(size_t)(bh + ty + r) * M2 + bm + tx];
  __syncthreads();
#pragma unroll
  for (int r = 0; r < 32; r += 8)
    out[(size_t)(bm + ty + r) * L_ + bh + tx] = tile[tx][ty + r];
}

// ---------------- exact fp32 rescore of candidates -> argmax offsets
__global__ __launch_bounds__(64) void rescore_k(const float* __restrict__ f,
                                                const float* __restrict__ bsrc,
                                                const float* __restrict__ normden,
                                                const int* __restrict__ cand,
                                                const int* __restrict__ candcnt,
                                                float* __restrict__ offout, int bi) {
  const int row = blockIdx.x;
  const int lane = threadIdx.x;
  const int h = row >> 6, w = row & 63;
  int cnt = candcnt[row];
  int bestl = 0;
  if (cnt <= 1) {
    bestl = cand[row * NCAND];
  } else {
    float bestv = -1e30f;
    bestl = 0x7fffffff;
    for (int ci = 0; ci < cnt; ++ci) {
      int l = cand[row * NCAND + ci];
      int i = l >> 6, j = l & 63;
      float dot = 0.f;
#pragma unroll
      for (int cc = 0; cc < 2; ++cc) {
        int ch = lane + 64 * cc;
        const float* fb = f + (((size_t)bi * C_ + ch) * HH) * WW;
        const float* bb = bsrc + (((size_t)bi * C_ + ch) * HH) * WW;
#pragma unroll
        for (int p = 0; p < 3; ++p)
#pragma unroll
          for (int q = 0; q < 3; ++q) {
            int y1 = h + p - 1, x1 = w + q - 1;
            int y2 = i + p - 1, x2 = j + q - 1;
            if ((unsigned)y1 < 64u && (unsigned)x1 < 64u &&
                (unsigned)y2 < 64u && (unsigned)x2 < 64u)
              dot += fb[(size_t)(2 * y1) * WW + 2 * x1] * bb[(size_t)(2 * y2) * WW + 2 * x2];
          }
      }
#pragma unroll
      for (int o = 32; o; o >>= 1) dot += __shfl_xor(dot, o);
      float s = dot / normden[l];
      if (s > bestv || (s == bestv && l < bestl)) { bestv = s; bestl = l; }
    }
  }
  if (lane == 0) {
    int istar = bestl >> 6, jstar = bestl & 63;
    offout[(size_t)bi * 8192 + row] = (float)(istar - h);
    offout[(size_t)bi * 8192 + L_ + row] = (float)(jstar - w);
  }
}

// ---------------- final transposed-conv gather from Z2[m][hw] (coalesced rows)
__global__ void gather_k(const float* __restrict__ Z2, float* __restrict__ yout, int bi) {
  int u = blockIdx.x, c = blockIdx.y;
  int t = threadIdx.x;  // 64 threads, each handles v=2t and v=2t+1
  int h0 = (u + 1) >> 1, p0 = (u + 1) & 1;
  int h1 = h0 - 1, p1 = p0 + 2;
  float a0 = 0.f, a1 = 0.f;
#pragma unroll
  for (int e = 0; e < 2; ++e) {
    int h = e ? h1 : h0;
    int p = e ? p1 : p0;
    if ((unsigned)h < 64u) {
      const float* zb = Z2 + (size_t)(c * 16 + p * 4) * L_ + h * 64;
      a0 += zb[1 * L_ + t];
      if (t >= 1) a0 += zb[3 * L_ + (t - 1)];
      if (t < 63) a1 += zb[0 * L_ + (t + 1)];
      a1 += zb[2 * L_ + t];
    }
  }
  size_t ybase = (((size_t)bi * C_ + c) * HH + u) * WW;
  yout[ybase + 2 * t] = a0 * 0.25f;
  yout[ybase + 2 * t + 1] = a1 * 0.25f;
}

extern "C" void kernel_launch(void* const* d_in, const int* in_sizes, int n_in,
                              void* d_out, int out_size, void* d_ws, size_t ws_size,
                              hipStream_t stream) {
  const float* f = (const float*)d_in[0];
  const float* b = (const float*)d_in[1];
  const float* mask = (const float*)d_in[2];
  float* out = (float*)d_out;
  char* ws = (char*)d_ws;

  size_t off = 0;
  float* mm = (float*)(ws + off);       off += 16384;
  float* normden = (float*)(ws + off);  off += 16384;
  int* cand = (int*)(ws + off);         off += (size_t)L_ * NCAND * 4;  // 256KB
  int* candcnt = (int*)(ws + off);      off += 16384;
  bf16* U = (bf16*)(ws + off);          off += (size_t)L_ * K1 * 2;     // 9.4MB
  bf16* FP = (bf16*)(ws + off);         off += (size_t)L_ * K1 * 2;     // 9.4MB
  bf16* BmT = (bf16*)(ws + off);        off += (size_t)M2 * L_ * 2;     // 16.8MB
  float* S = (float*)(ws + off);        off += (size_t)L_ * L_ * 4;     // 67.1MB
  float* Zt = (float*)(ws + off);       off += (size_t)M2 * L_ * 4;     // 33.5MB
  float* Z2 = (float*)(ws + off);       off += (size_t)M2 * L_ * 4;     // 33.5MB
  float* yout = out;
  float* offout = out + (size_t)B_ * C_ * HH * WW;

  compute_mm_k<<<16, 256, 0, stream>>>(mask, mm);
  for (int bi = 0; bi < B_; ++bi) {
    prep_u_k<<<L_, 256, 0, stream>>>(b, U, normden, bi);
    prep_fp_k<<<(L_ * K1 + 255) / 256, 256, 0, stream>>>(f, FP, bi);
    prep_bmatT_k<<<(M2 * L_ + 255) / 256, 256, 0, stream>>>(b, BmT, bi);
    gemm_bt<<<dim3(32, 32), 256, 0, stream>>>(FP, U, S, L_, L_, K1);
    softmax_spmv_k<<<L_, 256, 0, stream>>>(S, mm, BmT, Zt, cand, candcnt);
    rescore_k<<<L_, 64, 0, stream>>>(f, b, normden, cand, candcnt, offout, bi);
    transpose_k<<<dim3(M2 / 32, L_ / 32), 256, 0, stream>>>(Zt, Z2);
    gather_k<<<dim3(128, 128), 64, 0, stream>>>(Z2, yout, bi);
  }
}